// Round 1
// baseline (522.181 us; speedup 1.0000x reference)
//
#include <hip/hip_runtime.h>
#include <math.h>

#define BATCH 4
#define CIN   128
#define CO    64
#define NPIX  4096      // 64*64
#define TQ    64        // queries per block (flash)
#define TK    64        // keys per tile
#define KPAD  68        // 64 + 4 floats, keeps 16B alignment for float4 LDS ops
#define PPAD  66

// ---------------- Kernel 1: f,g,h projections -> Q,K,V in [B][N][CO] ----------------
__global__ __launch_bounds__(256) void proj_kernel(
    const float* __restrict__ x,
    const float* __restrict__ Wf, const float* __restrict__ bf,
    const float* __restrict__ Wg, const float* __restrict__ bg,
    const float* __restrict__ Wh, const float* __restrict__ bh,
    float* __restrict__ Q, float* __restrict__ K, float* __restrict__ V)
{
    __shared__ float xs[CIN][65];    // [c][n] pad 65: conflict-free
    __shared__ float Ws[CO][129];    // [o][c] pad 129: (o+c)%32 -> 2-way (free)

    int bid = blockIdx.x;
    int b   = bid >> 6;              // 64 n-tiles per batch
    int n0  = (bid & 63) << 6;
    int t   = threadIdx.x;

    const float* xb = x + (size_t)b * CIN * NPIX + n0;
    for (int idx = t; idx < CIN * 64; idx += 256) {
        int c = idx >> 6, n = idx & 63;
        xs[c][n] = xb[(size_t)c * NPIX + n];     // coalesced in n
    }

    const float* Wp[3]   = {Wf, Wg, Wh};
    const float* bp[3]   = {bf, bg, bh};
    float*       outp[3] = {Q, K, V};

    int o    = t & 63;
    int nsub = t >> 6;               // 0..3 (wave-uniform)

    for (int p = 0; p < 3; ++p) {
        __syncthreads();             // xs ready (p=0) / prev compute done (p>0)
        const float* W = Wp[p];
        for (int idx = t; idx < CO * CIN; idx += 256) {
            int oo = idx >> 7, cc = idx & 127;
            Ws[oo][cc] = W[idx];
        }
        __syncthreads();
        float bias = bp[p][o];
        float* dst = outp[p] + ((size_t)b * NPIX + n0) * CO;
        for (int j = 0; j < 16; ++j) {
            int n = (j << 2) + nsub; // wave-uniform n -> xs broadcast
            float acc = bias;
            #pragma unroll 8
            for (int c = 0; c < CIN; ++c)
                acc = fmaf(Ws[o][c], xs[c][n], acc);
            dst[(size_t)n * CO + o] = acc;       // coalesced in o
        }
    }
}

// ---------------- Kernel 2: fp32 flash attention, O = softmax(Q K^T) V ----------------
// 512 threads = 8 waves; thread t: q = t>>3 (0..63), sub = t&7.
// S phase: thread owns keys k = sub + 8*jk (jk 0..7).
// PV phase: thread owns dims d = sub*8 .. sub*8+7.
__global__ __launch_bounds__(512) void flash_kernel(
    const float* __restrict__ Q, const float* __restrict__ K,
    const float* __restrict__ V, float* __restrict__ O)
{
    __shared__ float Ks[TK][KPAD];
    __shared__ float Vs[TK][KPAD];
    __shared__ float Ps[TQ][PPAD];

    int bid = blockIdx.x;
    int b   = bid >> 6;              // 64 q-blocks per batch
    int n0  = (bid & 63) * TQ;
    int t   = threadIdx.x;
    int q   = t >> 3;
    int sub = t & 7;

    // Q row -> registers (8x redundant across sub lanes; L1 absorbs)
    float4 qv[16];
    const float4* Qrow = (const float4*)(Q + ((size_t)b * NPIX + n0 + q) * CO);
    #pragma unroll
    for (int i = 0; i < 16; ++i) qv[i] = Qrow[i];

    float  m = -INFINITY, l = 0.f;
    float4 o0 = {0.f,0.f,0.f,0.f}, o1 = {0.f,0.f,0.f,0.f};

    const float* Kb = K + (size_t)b * NPIX * CO;
    const float* Vb = V + (size_t)b * NPIX * CO;

    for (int kt = 0; kt < NPIX / TK; ++kt) {
        const float4* Ksrc = (const float4*)(Kb + (size_t)kt * TK * CO);
        const float4* Vsrc = (const float4*)(Vb + (size_t)kt * TK * CO);
        for (int idx = t; idx < TK * 16; idx += 512) {
            int rr = idx >> 4, ch = (idx & 15) << 2;
            *(float4*)&Ks[rr][ch] = Ksrc[idx];
            *(float4*)&Vs[rr][ch] = Vsrc[idx];
        }
        __syncthreads();

        // --- S = q . k for 8 keys ---
        float s[8];
        #pragma unroll
        for (int jk = 0; jk < 8; ++jk) {
            int k = sub + (jk << 3);             // 8 distinct 16B reads span all banks
            const float4* Krow = (const float4*)&Ks[k][0];
            float4 a = {0.f,0.f,0.f,0.f};
            #pragma unroll
            for (int i = 0; i < 16; ++i) {
                float4 kv = Krow[i];
                a.x = fmaf(qv[i].x, kv.x, a.x);
                a.y = fmaf(qv[i].y, kv.y, a.y);
                a.z = fmaf(qv[i].z, kv.z, a.z);
                a.w = fmaf(qv[i].w, kv.w, a.w);
            }
            s[jk] = (a.x + a.y) + (a.z + a.w);
        }

        // --- online softmax across the 8 lanes sharing q ---
        float mx = s[0];
        #pragma unroll
        for (int jk = 1; jk < 8; ++jk) mx = fmaxf(mx, s[jk]);
        #pragma unroll
        for (int off = 1; off < 8; off <<= 1) mx = fmaxf(mx, __shfl_xor(mx, off));
        float mnew = fmaxf(m, mx);
        float r = __expf(m - mnew);              // first iter: exp(-inf) = 0
        float p[8];
        float ls = 0.f;
        #pragma unroll
        for (int jk = 0; jk < 8; ++jk) { p[jk] = __expf(s[jk] - mnew); ls += p[jk]; }
        #pragma unroll
        for (int off = 1; off < 8; off <<= 1) ls += __shfl_xor(ls, off);
        l = l * r + ls;
        m = mnew;
        o0.x *= r; o0.y *= r; o0.z *= r; o0.w *= r;
        o1.x *= r; o1.y *= r; o1.z *= r; o1.w *= r;
        #pragma unroll
        for (int jk = 0; jk < 8; ++jk) Ps[q][sub + (jk << 3)] = p[jk];
        __syncthreads();

        // --- PV: o[d] += sum_k p[k] * V[k][d], d = sub*8..sub*8+7 ---
        #pragma unroll 8
        for (int k = 0; k < TK; ++k) {
            float pv = Ps[q][k];
            float4 v0 = *(const float4*)&Vs[k][sub << 3];
            float4 v1 = *(const float4*)&Vs[k][(sub << 3) + 4];
            o0.x = fmaf(pv, v0.x, o0.x);
            o0.y = fmaf(pv, v0.y, o0.y);
            o0.z = fmaf(pv, v0.z, o0.z);
            o0.w = fmaf(pv, v0.w, o0.w);
            o1.x = fmaf(pv, v1.x, o1.x);
            o1.y = fmaf(pv, v1.y, o1.y);
            o1.z = fmaf(pv, v1.z, o1.z);
            o1.w = fmaf(pv, v1.w, o1.w);
        }
        __syncthreads();             // protect Ks/Vs before next stage
    }

    float inv = 1.0f / l;
    o0.x *= inv; o0.y *= inv; o0.z *= inv; o0.w *= inv;
    o1.x *= inv; o1.y *= inv; o1.z *= inv; o1.w *= inv;
    float* Orow = O + ((size_t)b * NPIX + n0 + q) * CO + (sub << 3);
    *(float4*)Orow       = o0;
    *(float4*)(Orow + 4) = o1;
}

// ---------------- Kernel 3: out = gamma * (Wa @ O^T + ba) ----------------
__global__ __launch_bounds__(256) void outconv_kernel(
    const float* __restrict__ O, const float* __restrict__ Wa,
    const float* __restrict__ ba, const float* __restrict__ gamma,
    float* __restrict__ out)
{
    __shared__ float Os[64][KPAD];   // [n][c]
    __shared__ float Was[CO][KPAD];  // [o][c]

    int bid = blockIdx.x;
    int b   = bid >> 6;
    int n0  = (bid & 63) << 6;
    int t   = threadIdx.x;

    const float4* Osrc = (const float4*)(O + ((size_t)b * NPIX + n0) * CO);
    for (int idx = t; idx < 64 * 16; idx += 256) {
        int rr = idx >> 4, ch = (idx & 15) << 2;
        *(float4*)&Os[rr][ch] = Osrc[idx];
    }
    const float4* Wsrc = (const float4*)Wa;
    for (int idx = t; idx < 64 * 16; idx += 256) {
        int rr = idx >> 4, ch = (idx & 15) << 2;
        *(float4*)&Was[rr][ch] = Wsrc[idx];
    }
    __syncthreads();

    int n  = t & 63;
    int oB = (t >> 6) << 4;          // 16 outputs per thread
    float g = gamma[0];

    float orow[64];
    #pragma unroll
    for (int i = 0; i < 16; ++i)
        *(float4*)&orow[i << 2] = *(const float4*)&Os[n][i << 2];

    float* outb = out + (size_t)b * CO * NPIX + n0 + n;
    for (int j = 0; j < 16; ++j) {
        int o = oB + j;              // wave-uniform -> Was broadcast reads
        float acc = ba[o];
        #pragma unroll 16
        for (int c = 0; c < CO; ++c)
            acc = fmaf(Was[o][c], orow[c], acc);
        outb[(size_t)o * NPIX] = g * acc;   // coalesced in n
    }
}

extern "C" void kernel_launch(void* const* d_in, const int* in_sizes, int n_in,
                              void* d_out, int out_size, void* d_ws, size_t ws_size,
                              hipStream_t stream) {
    const float* x     = (const float*)d_in[0];
    const float* Wf    = (const float*)d_in[1];
    const float* bf    = (const float*)d_in[2];
    const float* Wg    = (const float*)d_in[3];
    const float* bg    = (const float*)d_in[4];
    const float* Wh    = (const float*)d_in[5];
    const float* bh    = (const float*)d_in[6];
    const float* Wa    = (const float*)d_in[7];
    const float* ba    = (const float*)d_in[8];
    const float* gamma = (const float*)d_in[9];
    float* out = (float*)d_out;

    const size_t mat = (size_t)BATCH * NPIX * CO;   // 1,048,576 floats = 4 MB
    float* Q = (float*)d_ws;
    float* K = Q + mat;
    float* V = K + mat;
    float* O = V + mat;

    proj_kernel<<<BATCH * (NPIX / 64), 256, 0, stream>>>(x, Wf, bf, Wg, bg, Wh, bh, Q, K, V);
    flash_kernel<<<BATCH * (NPIX / TQ), 512, 0, stream>>>(Q, K, V, O);
    outconv_kernel<<<BATCH * (NPIX / 64), 256, 0, stream>>>(O, Wa, ba, gamma, out);
}

// Round 2
// 178.788 us; speedup vs baseline: 2.9207x; 2.9207x over previous
//
#include <hip/hip_runtime.h>
#include <math.h>

#define BATCH 4
#define CIN   128
#define CO    64
#define NPIX  4096

typedef unsigned int  uint_t;
typedef unsigned short ushort_t;
typedef __bf16 bfx8 __attribute__((ext_vector_type(8)));
typedef float  f32x4 __attribute__((ext_vector_type(4)));

#define MFMA(a,b,c) __builtin_amdgcn_mfma_f32_16x16x32_bf16((a),(b),(c),0,0,0)
#define BC8(x) __builtin_bit_cast(bfx8,(x))

static __device__ __forceinline__ ushort_t f2bf(float f) {
    uint_t u = __builtin_bit_cast(uint_t, f);
    u = (u + 0x7fffu + ((u >> 16) & 1u)) >> 16;   // RNE
    return (ushort_t)u;
}

// ---------------- Kernel 1: projections -> Q,K bf16 [B][N][64]; V bf16 [B][64][N] ----------------
__global__ __launch_bounds__(256) void proj_kernel(
    const float* __restrict__ x,
    const float* __restrict__ Wf, const float* __restrict__ bf,
    const float* __restrict__ Wg, const float* __restrict__ bg,
    const float* __restrict__ Wh, const float* __restrict__ bh,
    ushort_t* __restrict__ Q, ushort_t* __restrict__ K, ushort_t* __restrict__ V)
{
    __shared__ float xs[CIN][65];
    __shared__ float Ws[CO][129];
    __shared__ ushort_t vsb[64][72];   // V transpose buffer (row 144B, 16B-aligned)

    int bid = blockIdx.x;
    int b   = bid >> 6;
    int n0  = (bid & 63) << 6;
    int t   = threadIdx.x;

    const float* xb = x + (size_t)b * CIN * NPIX + n0;
    for (int idx = t; idx < CIN * 64; idx += 256) {
        int cc = idx >> 6, n = idx & 63;
        xs[cc][n] = xb[(size_t)cc * NPIX + n];
    }

    const float* Wp[3] = {Wf, Wg, Wh};
    const float* bp[3] = {bf, bg, bh};
    int o = t & 63, nsub = t >> 6;

    for (int p = 0; p < 3; ++p) {
        __syncthreads();
        const float* W = Wp[p];
        for (int idx = t; idx < CO * CIN; idx += 256) {
            int oo = idx >> 7, cc = idx & 127;
            Ws[oo][cc] = W[idx];
        }
        __syncthreads();
        float bias = bp[p][o];
        ushort_t* dst = (p == 0 ? Q : K) + ((size_t)b * NPIX + n0) * CO;
        for (int j = 0; j < 16; ++j) {
            int n = (j << 2) + nsub;
            float acc = bias;
            #pragma unroll 8
            for (int ci = 0; ci < CIN; ++ci)
                acc = fmaf(Ws[o][ci], xs[ci][n], acc);
            if (p < 2) dst[(size_t)n * CO + o] = f2bf(acc);
            else       vsb[o][n] = f2bf(acc);
        }
    }
    __syncthreads();
    // cooperative transposed V store: coalesced along n
    {
        int oo = t >> 2, nc = t & 3;
        ushort_t* Vr = V + (size_t)b * CO * NPIX + (size_t)oo * NPIX + n0 + (nc << 4);
        uint4 a = *(const uint4*)&vsb[oo][nc << 4];
        uint4 bv = *(const uint4*)&vsb[oo][(nc << 4) + 8];
        *(uint4*)Vr = a;
        *(uint4*)(Vr + 8) = bv;
    }
}

// ---------------- Kernel 2: bf16-MFMA flash attention ----------------
// 256 threads = 4 waves. Block: 64 queries. KV tile: 128 keys staged shared in LDS;
// wave w processes key slice [32w,32w+32) of every tile (split-K), merged at end.
// QK^T swapped (D[key][q]) and PV swapped (D[d][q]) so softmax stats are lane-local (q = lane&15).
// LDS map: [0,16384) K tile [128k][64d] bf16, slot-swizzled ^key&7
//          [16384,32768) Vt tile [64d][128k] bf16, slot-swizzled ^d&7
//          [32768,53248) per-wave P [64q][32k] bf16, 80B row pitch
// Epilogue overlays: ml @32768 (2KB), Po @34816 (16KB), pub buffers in K/Vt regions.
#define POFF 32768
#define PSTR 80

__global__ __launch_bounds__(256, 1) void flash_kernel(
    const ushort_t* __restrict__ Q, const ushort_t* __restrict__ K,
    const ushort_t* __restrict__ V, float* __restrict__ O)
{
    __shared__ __align__(16) char smem[53248];

    int bid = blockIdx.x, b = bid >> 6, n0 = (bid & 63) << 6, t = threadIdx.x;
    int w = t >> 6, lane = t & 63, c = lane & 15, g = lane >> 4;

    const ushort_t* Qb = Q + ((size_t)b * NPIX + n0) * CO;
    const ushort_t* Kb = K + (size_t)b * NPIX * CO;
    const ushort_t* Vb = V + (size_t)b * CO * NPIX;

    // Q fragments (B-operand): col q = 16*qs + c, d = 32*ds + 8*g + j
    uint4 qf[4][2];
    #pragma unroll
    for (int qs = 0; qs < 4; ++qs)
        #pragma unroll
        for (int ds = 0; ds < 2; ++ds)
            qf[qs][ds] = *(const uint4*)(Qb + ((qs << 4) + c) * CO + (ds << 5) + (g << 3));

    f32x4 oac[4][4];   // [ds][qs]: O[d][q], d = 16ds+4g+reg, q = 16qs+c
    #pragma unroll
    for (int i = 0; i < 4; ++i)
        #pragma unroll
        for (int j = 0; j < 4; ++j)
            oac[i][j] = (f32x4){0.f, 0.f, 0.f, 0.f};
    float mreg[4] = {-INFINITY, -INFINITY, -INFINITY, -INFINITY};
    float lreg[4] = {0.f, 0.f, 0.f, 0.f};

    char* Pmy = smem + POFF + w * 5120;

    for (int kt = 0; kt < 32; ++kt) {
        // ---- stage K [128][64] and Vt [64][128] (bf16, slot-swizzled) ----
        #pragma unroll
        for (int i = 0; i < 4; ++i) {
            int ci = t + (i << 8);                 // 0..1023
            int key = ci >> 3, cc = ci & 7;
            uint4 vv = *(const uint4*)(Kb + (size_t)((kt << 7) + key) * CO + (cc << 3));
            *(uint4*)(smem + (key << 7) + (((cc ^ (key & 7))) << 4)) = vv;
        }
        #pragma unroll
        for (int i = 0; i < 4; ++i) {
            int ci = t + (i << 8);
            int d = ci >> 4, cc = ci & 15;
            uint4 vv = *(const uint4*)(Vb + (size_t)d * NPIX + (kt << 7) + (cc << 3));
            int slot = cc ^ (d & 7);               // XOR within low 3 bits only
            *(uint4*)(smem + 16384 + (d << 8) + (slot << 4)) = vv;
        }
        __syncthreads();

        // ---- QK^T: S[key][q], key slice 32w..32w+31 ----
        f32x4 sac[2][4];
        #pragma unroll
        for (int s = 0; s < 2; ++s)
            #pragma unroll
            for (int qs = 0; qs < 4; ++qs)
                sac[s][qs] = (f32x4){0.f, 0.f, 0.f, 0.f};

        #pragma unroll
        for (int s = 0; s < 2; ++s) {
            int key = (w << 5) + (s << 4) + c;
            int sw = key & 7;
            uint4 kf0 = *(const uint4*)(smem + (key << 7) + ((((0 << 2) | g) ^ sw) << 4));
            uint4 kf1 = *(const uint4*)(smem + (key << 7) + ((((1 << 2) | g) ^ sw) << 4));
            #pragma unroll
            for (int qs = 0; qs < 4; ++qs) {
                sac[s][qs] = MFMA(BC8(kf0), BC8(qf[qs][0]), sac[s][qs]);
                sac[s][qs] = MFMA(BC8(kf1), BC8(qf[qs][1]), sac[s][qs]);
            }
        }

        // ---- online softmax (per lane: 4 queries x 8 keys) + P pack ----
        #pragma unroll
        for (int qs = 0; qs < 4; ++qs) {
            float mx = sac[0][qs][0];
            #pragma unroll
            for (int j = 1; j < 4; ++j) mx = fmaxf(mx, sac[0][qs][j]);
            #pragma unroll
            for (int j = 0; j < 4; ++j) mx = fmaxf(mx, sac[1][qs][j]);
            mx = fmaxf(mx, __shfl_xor(mx, 16));
            mx = fmaxf(mx, __shfl_xor(mx, 32));
            float mn = fmaxf(mreg[qs], mx);
            float r  = __expf(mreg[qs] - mn);
            float ps[8];
            float ls = 0.f;
            #pragma unroll
            for (int s = 0; s < 2; ++s)
                #pragma unroll
                for (int j = 0; j < 4; ++j) {
                    float p = __expf(sac[s][qs][j] - mn);
                    ps[(s << 2) + j] = p;
                    ls += p;
                }
            ls += __shfl_xor(ls, 16);
            ls += __shfl_xor(ls, 32);
            lreg[qs] = lreg[qs] * r + ls;
            mreg[qs] = mn;
            #pragma unroll
            for (int ds = 0; ds < 4; ++ds) oac[ds][qs] *= r;

            int q = (qs << 4) + c;
            #pragma unroll
            for (int s = 0; s < 2; ++s) {
                uint2 pk;
                pk.x = (uint_t)f2bf(ps[(s << 2) + 0]) | ((uint_t)f2bf(ps[(s << 2) + 1]) << 16);
                pk.y = (uint_t)f2bf(ps[(s << 2) + 2]) | ((uint_t)f2bf(ps[(s << 2) + 3]) << 16);
                *(uint2*)(Pmy + q * PSTR + (s << 5) + (g << 3)) = pk;
            }
        }

        // ---- PV: O[d][q] += Vt[d][k] * P[k][q] over wave's 32-key slice ----
        uint4 vf[4], pf[4];
        #pragma unroll
        for (int ds = 0; ds < 4; ++ds) {
            int d = (ds << 4) + c;
            int slot = (((w << 2) | g)) ^ (d & 7);
            vf[ds] = *(const uint4*)(smem + 16384 + (d << 8) + (slot << 4));
        }
        #pragma unroll
        for (int qs = 0; qs < 4; ++qs)
            pf[qs] = *(const uint4*)(Pmy + ((qs << 4) + c) * PSTR + (g << 4));
        #pragma unroll
        for (int ds = 0; ds < 4; ++ds)
            #pragma unroll
            for (int qs = 0; qs < 4; ++qs)
                oac[ds][qs] = MFMA(BC8(vf[ds]), BC8(pf[qs]), oac[ds][qs]);

        __syncthreads();
    }

    // ---------------- split-K merge across 4 waves ----------------
    float* mlb = (float*)(smem + POFF);   // m: [w][0..63], l: [w][64..127]
    if (lane < 16) {
        #pragma unroll
        for (int qs = 0; qs < 4; ++qs) {
            mlb[(w << 7) + (qs << 4) + lane]      = mreg[qs];
            mlb[(w << 7) + 64 + (qs << 4) + lane] = lreg[qs];
        }
    }
    if (w >= 2) {   // publish raw O2,O3 into K / Vt regions
        char* pub = smem + ((w - 2) << 14);
        #pragma unroll
        for (int ds = 0; ds < 4; ++ds)
            #pragma unroll
            for (int qs = 0; qs < 4; ++qs) {
                int q = (qs << 4) + c;
                int slot = (((ds << 2) | g)) ^ (q & 7);
                *(f32x4*)(pub + (q << 8) + (slot << 4)) = oac[ds][qs];
            }
    }
    __syncthreads();

    float aw[4][4], Lq[4];
    #pragma unroll
    for (int qs = 0; qs < 4; ++qs) {
        int q = (qs << 4) + c;
        float m0 = mlb[q], m1 = mlb[128 + q], m2 = mlb[256 + q], m3 = mlb[384 + q];
        float M  = fmaxf(fmaxf(m0, m1), fmaxf(m2, m3));
        float a0 = __expf(m0 - M), a1 = __expf(m1 - M), a2 = __expf(m2 - M), a3 = __expf(m3 - M);
        Lq[qs] = a0 * mlb[64 + q] + a1 * mlb[192 + q] + a2 * mlb[320 + q] + a3 * mlb[448 + q];
        aw[0][qs] = a0; aw[1][qs] = a1; aw[2][qs] = a2; aw[3][qs] = a3;
    }
    if (w == 0) {
        #pragma unroll
        for (int ds = 0; ds < 4; ++ds)
            #pragma unroll
            for (int qs = 0; qs < 4; ++qs) {
                int q = (qs << 4) + c;
                int slot = (((ds << 2) | g)) ^ (q & 7);
                f32x4 o2 = *(const f32x4*)(smem + (q << 8) + (slot << 4));
                oac[ds][qs] = aw[0][qs] * oac[ds][qs] + aw[2][qs] * o2;
            }
    }
    if (w == 1) {
        #pragma unroll
        for (int ds = 0; ds < 4; ++ds)
            #pragma unroll
            for (int qs = 0; qs < 4; ++qs) {
                int q = (qs << 4) + c;
                int slot = (((ds << 2) | g)) ^ (q & 7);
                f32x4 o3 = *(const f32x4*)(smem + 16384 + (q << 8) + (slot << 4));
                oac[ds][qs] = aw[1][qs] * oac[ds][qs] + aw[3][qs] * o3;
            }
    }
    __syncthreads();
    if (w == 1) {   // publish O1' into K region (wave0 done reading O2)
        #pragma unroll
        for (int ds = 0; ds < 4; ++ds)
            #pragma unroll
            for (int qs = 0; qs < 4; ++qs) {
                int q = (qs << 4) + c;
                int slot = (((ds << 2) | g)) ^ (q & 7);
                *(f32x4*)(smem + (q << 8) + (slot << 4)) = oac[ds][qs];
            }
    }
    __syncthreads();
    char* Po = smem + POFF + 2048;
    if (w == 0) {
        #pragma unroll
        for (int ds = 0; ds < 4; ++ds)
            #pragma unroll
            for (int qs = 0; qs < 4; ++qs) {
                int q = (qs << 4) + c;
                int slot = (((ds << 2) | g)) ^ (q & 7);
                f32x4 o1 = *(const f32x4*)(smem + (q << 8) + (slot << 4));
                f32x4 of = (oac[ds][qs] + o1) * (1.0f / Lq[qs]);
                *(f32x4*)(Po + (q << 8) + (slot << 4)) = of;
            }
    }
    __syncthreads();
    // cooperative coalesced store of O [B][N][64] fp32
    {
        float* Og = O + ((size_t)b * NPIX + n0) * CO;
        int q = t >> 2, ch = t & 3;
        #pragma unroll
        for (int i = 0; i < 4; ++i) {
            int slot = (((ch << 2) | i)) ^ (q & 7);
            f32x4 v = *(const f32x4*)(Po + (q << 8) + (slot << 4));
            *(f32x4*)(Og + (size_t)q * CO + (ch << 4) + (i << 2)) = v;
        }
    }
}

// ---------------- Kernel 3: out = gamma * (Wa @ O^T + ba) ----------------
__global__ __launch_bounds__(256) void outconv_kernel(
    const float* __restrict__ O, const float* __restrict__ Wa,
    const float* __restrict__ ba, const float* __restrict__ gamma,
    float* __restrict__ out)
{
    __shared__ float Os[64][68];
    __shared__ float Was[CO][68];

    int bid = blockIdx.x;
    int b   = bid >> 6;
    int n0  = (bid & 63) << 6;
    int t   = threadIdx.x;

    const float4* Osrc = (const float4*)(O + ((size_t)b * NPIX + n0) * CO);
    for (int idx = t; idx < 64 * 16; idx += 256) {
        int rr = idx >> 4, ch = (idx & 15) << 2;
        *(float4*)&Os[rr][ch] = Osrc[idx];
    }
    const float4* Wsrc = (const float4*)Wa;
    for (int idx = t; idx < 64 * 16; idx += 256) {
        int rr = idx >> 4, ch = (idx & 15) << 2;
        *(float4*)&Was[rr][ch] = Wsrc[idx];
    }
    __syncthreads();

    int n  = t & 63;
    int oB = (t >> 6) << 4;
    float gm = gamma[0];

    float orow[64];
    #pragma unroll
    for (int i = 0; i < 16; ++i)
        *(float4*)&orow[i << 2] = *(const float4*)&Os[n][i << 2];

    float* outb = out + (size_t)b * CO * NPIX + n0 + n;
    for (int j = 0; j < 16; ++j) {
        int o = oB + j;
        float acc = ba[o];
        #pragma unroll 16
        for (int ci = 0; ci < CO; ++ci)
            acc = fmaf(Was[o][ci], orow[ci], acc);
        outb[(size_t)o * NPIX] = gm * acc;
    }
}

extern "C" void kernel_launch(void* const* d_in, const int* in_sizes, int n_in,
                              void* d_out, int out_size, void* d_ws, size_t ws_size,
                              hipStream_t stream) {
    const float* x     = (const float*)d_in[0];
    const float* Wf    = (const float*)d_in[1];
    const float* bf    = (const float*)d_in[2];
    const float* Wg    = (const float*)d_in[3];
    const float* bg    = (const float*)d_in[4];
    const float* Wh    = (const float*)d_in[5];
    const float* bh    = (const float*)d_in[6];
    const float* Wa    = (const float*)d_in[7];
    const float* ba    = (const float*)d_in[8];
    const float* gamma = (const float*)d_in[9];
    float* out = (float*)d_out;

    const size_t matb = (size_t)BATCH * NPIX * CO;        // elements
    ushort_t* Q = (ushort_t*)d_ws;                        // 2 MB
    ushort_t* K = Q + matb;                               // 2 MB
    ushort_t* V = K + matb;                               // 2 MB (transposed layout)
    float*    O = (float*)((char*)d_ws + 6 * 1024 * 1024);// 4 MB

    proj_kernel<<<BATCH * (NPIX / 64), 256, 0, stream>>>(x, Wf, bf, Wg, bg, Wh, bh, Q, K, V);
    flash_kernel<<<BATCH * (NPIX / 64), 256, 0, stream>>>(Q, K, V, O);
    outconv_kernel<<<BATCH * (NPIX / 64), 256, 0, stream>>>(O, Wa, ba, gamma, out);
}

// Round 4
// 83.244 us; speedup vs baseline: 6.2729x; 2.1477x over previous
//
#include <hip/hip_runtime.h>
#include <math.h>

#define BATCH 4
#define CIN   128
#define CO    64
#define NPIX  4096
#define POFF  32768

typedef unsigned int   uint_t;
typedef unsigned short ushort_t;
typedef __bf16 bfx8 __attribute__((ext_vector_type(8)));
typedef float  f32x4 __attribute__((ext_vector_type(4)));

#define MFMA(a,b,c) __builtin_amdgcn_mfma_f32_16x16x32_bf16((a),(b),(c),0,0,0)
#define BC8(x) __builtin_bit_cast(bfx8,(x))

static __device__ __forceinline__ ushort_t f2bf(float f) {
    uint_t u = __builtin_bit_cast(uint_t, f);
    u = (u + 0x7fffu + ((u >> 16) & 1u)) >> 16;   // RNE
    return (ushort_t)u;
}
static __device__ __forceinline__ float bf2f(ushort_t h) {
    return __builtin_bit_cast(float, (uint_t)h << 16);
}
static __device__ __forceinline__ uint_t pk2(float a, float b) {
    return (uint_t)f2bf(a) | ((uint_t)f2bf(b) << 16);
}

// ---------------- Kernel 0: convert Wf,Wg,Wh,Wa to bf16 in ws ----------------
// ws layout (ushort elems): [0,8192) Wf | [8192,16384) Wg | [16384,24576) Wh | [24576,28672) Wa
__global__ __launch_bounds__(256) void wconv_kernel(
    const float* __restrict__ Wf, const float* __restrict__ Wg,
    const float* __restrict__ Wh, const float* __restrict__ Wa,
    ushort_t* __restrict__ Wb)
{
    int gid = blockIdx.x * 256 + threadIdx.x;
    for (int e = gid; e < 28672; e += 4096) {
        float v;
        if      (e < 8192)  v = Wf[e];
        else if (e < 16384) v = Wg[e - 8192];
        else if (e < 24576) v = Wh[e - 16384];
        else                v = Wa[e - 24576];
        Wb[e] = f2bf(v);
    }
}

// ---------------- Kernel 1: MFMA projections -> Q,K bf16 [B][N][64]; V bf16 [B][64][N] ----------------
// 256 thr = 4 waves; block covers 64 n. Wave w: n-rows n0+16w..+15.
// x split hi/lo bf16 for near-fp32 input precision; two MFMA accumulations per k-tile.
__global__ __launch_bounds__(256) void proj_kernel(
    const float* __restrict__ x, const ushort_t* __restrict__ Wb,
    const float* __restrict__ bf_, const float* __restrict__ bg_, const float* __restrict__ bh_,
    ushort_t* __restrict__ Q, ushort_t* __restrict__ K, ushort_t* __restrict__ V)
{
    __shared__ ushort_t xs[CIN][70];   // hi
    __shared__ ushort_t xl[CIN][70];   // lo

    int bid = blockIdx.x, b = bid >> 6, n0 = (bid & 63) << 6, t = threadIdx.x;
    int w = t >> 6, lane = t & 63, cl = lane & 15, g = (lane >> 4) & 3;

    const float* xb = x + (size_t)b * CIN * NPIX + n0;
    #pragma unroll
    for (int i = 0; i < 8; ++i) {
        int idx = t + (i << 8);          // 0..2047 ; c = idx>>4, n4 = idx&15
        int cc = idx >> 4, n4 = idx & 15;
        float4 v = *(const float4*)(xb + (size_t)cc * NPIX + (n4 << 2));
        ushort_t h0 = f2bf(v.x), h1 = f2bf(v.y), h2 = f2bf(v.z), h3 = f2bf(v.w);
        ushort_t* dh = &xs[cc][n4 << 2];
        *(uint_t*)dh       = (uint_t)h0 | ((uint_t)h1 << 16);
        *(uint_t*)(dh + 2) = (uint_t)h2 | ((uint_t)h3 << 16);
        ushort_t* dl = &xl[cc][n4 << 2];
        *(uint_t*)dl       = pk2(v.x - bf2f(h0), v.y - bf2f(h1));
        *(uint_t*)(dl + 2) = pk2(v.z - bf2f(h2), v.w - bf2f(h3));
    }
    __syncthreads();

    // A fragments: rows n = wave base + cl, k = 32ks + 8g + j
    uint4 aq[4], al[4];
    int col = (w << 4) + cl;             // <-- bug fix: wave offset
    #pragma unroll
    for (int ks = 0; ks < 4; ++ks) {
        ushort_t av[8], lv[8];
        #pragma unroll
        for (int j = 0; j < 8; ++j) {
            av[j] = xs[(ks << 5) + (g << 3) + j][col];
            lv[j] = xl[(ks << 5) + (g << 3) + j][col];
        }
        uint4 a, l;
        a.x = (uint_t)av[0] | ((uint_t)av[1] << 16);
        a.y = (uint_t)av[2] | ((uint_t)av[3] << 16);
        a.z = (uint_t)av[4] | ((uint_t)av[5] << 16);
        a.w = (uint_t)av[6] | ((uint_t)av[7] << 16);
        l.x = (uint_t)lv[0] | ((uint_t)lv[1] << 16);
        l.y = (uint_t)lv[2] | ((uint_t)lv[3] << 16);
        l.z = (uint_t)lv[4] | ((uint_t)lv[5] << 16);
        l.w = (uint_t)lv[6] | ((uint_t)lv[7] << 16);
        aq[ks] = a; al[ks] = l;
    }

    const float* bps[3] = {bf_, bg_, bh_};
    int nb = n0 + (w << 4);              // wave n-base

    for (int p = 0; p < 3; ++p) {
        const ushort_t* Wp = Wb + p * 8192;
        f32x4 acc[4];
        #pragma unroll
        for (int ot = 0; ot < 4; ++ot) acc[ot] = (f32x4){0.f,0.f,0.f,0.f};
        #pragma unroll
        for (int ks = 0; ks < 4; ++ks) {
            #pragma unroll
            for (int ot = 0; ot < 4; ++ot) {
                uint4 bq = *(const uint4*)(Wp + (((ot << 4) + cl) << 7) + (ks << 5) + (g << 3));
                acc[ot] = MFMA(BC8(aq[ks]), BC8(bq), acc[ot]);
                acc[ot] = MFMA(BC8(al[ks]), BC8(bq), acc[ot]);
            }
        }
        if (p < 2) {
            ushort_t* dst = (p == 0 ? Q : K) + ((size_t)b * NPIX + nb) * CO;
            #pragma unroll
            for (int ot = 0; ot < 4; ++ot) {
                float bias = bps[p][(ot << 4) + cl];
                #pragma unroll
                for (int r = 0; r < 4; ++r)
                    dst[(size_t)((g << 2) + r) * CO + (ot << 4) + cl] = f2bf(acc[ot][r] + bias);
            }
        } else {
            #pragma unroll
            for (int ot = 0; ot < 4; ++ot) {
                float bias = bps[p][(ot << 4) + cl];
                uint2 pk;
                pk.x = pk2(acc[ot][0] + bias, acc[ot][1] + bias);
                pk.y = pk2(acc[ot][2] + bias, acc[ot][3] + bias);
                ushort_t* Vd = V + (size_t)b * CO * NPIX + (size_t)((ot << 4) + cl) * NPIX + nb + (g << 2);
                *(uint2*)Vd = pk;
            }
        }
    }
}

// ---------------- Kernel 2: bf16-MFMA flash attention + fused output conv ----------------
// 512 thr = 8 waves. h = w>>2 (q-half: 32 q), ws = w&3 (32-key slice of the 128-key tile).
// LDS: [0,16384) K [128key][64d] swz ^key&7 | [16384,32768) Vt [64d][128k] swz ^d&7
//      [32768,53248) per-wave P [32q][32k] bf16 pitch 80B
// Epilogue overlays: mlb/llb @POFF (4KB, on dead P) ; Po f32 [64q][64d] swz @0 (K region) ;
//                    Pb bf16 [64q][72] @16384 (Vt region).
__global__ __launch_bounds__(512, 2) void flash_kernel(
    const ushort_t* __restrict__ Q, const ushort_t* __restrict__ K,
    const ushort_t* __restrict__ V, const ushort_t* __restrict__ Wb,
    const float* __restrict__ ba, const float* __restrict__ gamma,
    float* __restrict__ out)
{
    __shared__ __align__(16) char smem[53248];

    int bid = blockIdx.x, b = bid >> 6, n0 = (bid & 63) << 6, t = threadIdx.x;
    int w = t >> 6, lane = t & 63, c = lane & 15, g = (lane >> 4) & 3;
    int h = w >> 2, ws = w & 3;

    const ushort_t* Qb = Q + ((size_t)b * NPIX + n0) * CO;
    const ushort_t* Kb = K + (size_t)b * NPIX * CO;
    const ushort_t* Vb = V + (size_t)b * CO * NPIX;

    uint4 qf[2][2];
    #pragma unroll
    for (int qs = 0; qs < 2; ++qs)
        #pragma unroll
        for (int ds = 0; ds < 2; ++ds)
            qf[qs][ds] = *(const uint4*)(Qb + ((h << 5) + (qs << 4) + c) * CO + (ds << 5) + (g << 3));

    f32x4 oac[4][2];
    #pragma unroll
    for (int i = 0; i < 4; ++i)
        #pragma unroll
        for (int j = 0; j < 2; ++j) oac[i][j] = (f32x4){0.f,0.f,0.f,0.f};
    float mreg[2] = {-INFINITY, -INFINITY};
    float lreg[2] = {0.f, 0.f};

    char* Pmy = smem + POFF + w * 2560;

    for (int kt = 0; kt < 32; ++kt) {
        #pragma unroll
        for (int i = 0; i < 2; ++i) {
            int ci = t + (i << 9);
            int key = ci >> 3, cc = ci & 7;
            uint4 vv = *(const uint4*)(Kb + (size_t)((kt << 7) + key) * CO + (cc << 3));
            *(uint4*)(smem + (key << 7) + ((cc ^ (key & 7)) << 4)) = vv;
        }
        #pragma unroll
        for (int i = 0; i < 2; ++i) {
            int ci = t + (i << 9);
            int d = ci >> 4, cc = ci & 15;
            uint4 vv = *(const uint4*)(Vb + (size_t)d * NPIX + (kt << 7) + (cc << 3));
            *(uint4*)(smem + 16384 + (d << 8) + ((cc ^ (d & 7)) << 4)) = vv;
        }
        __syncthreads();

        // QK^T: S[key][q] for 32-key slice ws
        f32x4 sac[2][2];
        #pragma unroll
        for (int s = 0; s < 2; ++s)
            #pragma unroll
            for (int qs = 0; qs < 2; ++qs) sac[s][qs] = (f32x4){0.f,0.f,0.f,0.f};
        #pragma unroll
        for (int s = 0; s < 2; ++s) {
            int key = (ws << 5) + (s << 4) + c;
            int sw = key & 7;
            uint4 kf0 = *(const uint4*)(smem + (key << 7) + ((g ^ sw) << 4));
            uint4 kf1 = *(const uint4*)(smem + (key << 7) + (((4 | g) ^ sw) << 4));
            #pragma unroll
            for (int qs = 0; qs < 2; ++qs) {
                sac[s][qs] = MFMA(BC8(kf0), BC8(qf[qs][0]), sac[s][qs]);
                sac[s][qs] = MFMA(BC8(kf1), BC8(qf[qs][1]), sac[s][qs]);
            }
        }

        // online softmax (per lane: 2 queries x 8 keys of the slice)
        #pragma unroll
        for (int qs = 0; qs < 2; ++qs) {
            float mx = sac[0][qs][0];
            #pragma unroll
            for (int j = 1; j < 4; ++j) mx = fmaxf(mx, sac[0][qs][j]);
            #pragma unroll
            for (int j = 0; j < 4; ++j) mx = fmaxf(mx, sac[1][qs][j]);
            mx = fmaxf(mx, __shfl_xor(mx, 16));
            mx = fmaxf(mx, __shfl_xor(mx, 32));
            float mn = fmaxf(mreg[qs], mx);
            float r  = __expf(mreg[qs] - mn);
            float ps[8], ls = 0.f;
            #pragma unroll
            for (int s = 0; s < 2; ++s)
                #pragma unroll
                for (int j = 0; j < 4; ++j) {
                    float p = __expf(sac[s][qs][j] - mn);
                    ps[(s << 2) + j] = p; ls += p;
                }
            ls += __shfl_xor(ls, 16);
            ls += __shfl_xor(ls, 32);
            lreg[qs] = lreg[qs] * r + ls;
            mreg[qs] = mn;
            #pragma unroll
            for (int ds = 0; ds < 4; ++ds) oac[ds][qs] *= r;
            int ql = (qs << 4) + c;
            #pragma unroll
            for (int s = 0; s < 2; ++s) {
                uint2 pk;
                pk.x = pk2(ps[(s << 2) + 0], ps[(s << 2) + 1]);
                pk.y = pk2(ps[(s << 2) + 2], ps[(s << 2) + 3]);
                *(uint2*)(Pmy + ql * 80 + (s << 5) + (g << 3)) = pk;
            }
        }

        // PV over the wave's 32-key slice
        uint4 vf[4], pf[2];
        #pragma unroll
        for (int ds = 0; ds < 4; ++ds) {
            int d = (ds << 4) + c;
            vf[ds] = *(const uint4*)(smem + 16384 + (d << 8) + ((((ws << 2) | g) ^ (d & 7)) << 4));
        }
        #pragma unroll
        for (int qs = 0; qs < 2; ++qs)
            pf[qs] = *(const uint4*)(Pmy + ((qs << 4) + c) * 80 + (g << 4));
        #pragma unroll
        for (int ds = 0; ds < 4; ++ds)
            #pragma unroll
            for (int qs = 0; qs < 2; ++qs)
                oac[ds][qs] = MFMA(BC8(vf[ds]), BC8(pf[qs]), oac[ds][qs]);

        __syncthreads();
    }

    // ---- stats exchange ----
    float* mlb = (float*)(smem + POFF);
    float* llb = (float*)(smem + POFF + 2048);
    if (lane < 16) {
        #pragma unroll
        for (int qs = 0; qs < 2; ++qs) {
            mlb[(w << 6) + (h << 5) + (qs << 4) + lane] = mreg[qs];
            llb[(w << 6) + (h << 5) + (qs << 4) + lane] = lreg[qs];
        }
    }
    __syncthreads();

    float fac[2];
    #pragma unroll
    for (int qs = 0; qs < 2; ++qs) {
        int q = (h << 5) + (qs << 4) + c;
        int base = h << 2;
        float m0 = mlb[((base + 0) << 6) + q], m1 = mlb[((base + 1) << 6) + q];
        float m2 = mlb[((base + 2) << 6) + q], m3 = mlb[((base + 3) << 6) + q];
        float M  = fmaxf(fmaxf(m0, m1), fmaxf(m2, m3));
        float a0 = __expf(m0 - M), a1 = __expf(m1 - M), a2 = __expf(m2 - M), a3 = __expf(m3 - M);
        float L  = a0 * llb[((base + 0) << 6) + q] + a1 * llb[((base + 1) << 6) + q]
                 + a2 * llb[((base + 2) << 6) + q] + a3 * llb[((base + 3) << 6) + q];
        float aw = (ws == 0) ? a0 : (ws == 1) ? a1 : (ws == 2) ? a2 : a3;
        fac[qs] = aw / L;
    }
    #pragma unroll
    for (int ds = 0; ds < 4; ++ds)
        #pragma unroll
        for (int qs = 0; qs < 2; ++qs) oac[ds][qs] *= fac[qs];

    // ---- accumulate scaled partials into Po f32 (K region), rounds ws = 0,1,2 ----
    for (int r = 0; r < 3; ++r) {
        if (ws == r) {
            #pragma unroll
            for (int ds = 0; ds < 4; ++ds)
                #pragma unroll
                for (int qs = 0; qs < 2; ++qs) {
                    int q = (h << 5) + (qs << 4) + c;
                    int off = (q << 8) + ((((ds << 2) | g) ^ (q & 7)) << 4);
                    f32x4 v = oac[ds][qs];
                    if (r > 0) v += *(const f32x4*)(smem + off);
                    *(f32x4*)(smem + off) = v;
                }
        }
        __syncthreads();
    }
    // round 3: final add -> bf16 Pb (Vt region)
    ushort_t* Pb = (ushort_t*)(smem + 16384);
    if (ws == 3) {
        #pragma unroll
        for (int ds = 0; ds < 4; ++ds)
            #pragma unroll
            for (int qs = 0; qs < 2; ++qs) {
                int q = (h << 5) + (qs << 4) + c;
                int off = (q << 8) + ((((ds << 2) | g) ^ (q & 7)) << 4);
                f32x4 v = oac[ds][qs] + *(const f32x4*)(smem + off);
                uint2 pk;
                pk.x = pk2(v[0], v[1]);
                pk.y = pk2(v[2], v[3]);
                *(uint2*)(Pb + q * 72 + (ds << 4) + (g << 2)) = pk;
            }
    }
    __syncthreads();

    // ---- fused outconv: out[o][q] = gamma*(Wa[o][:] . Pb[q][:] + ba[o]) ----
    const ushort_t* Wab = Wb + 24576;
    float gm = gamma[0];
    int ot = w >> 1, qtb = (w & 1) << 1;
    f32x4 acc2[2] = {(f32x4){0.f,0.f,0.f,0.f}, (f32x4){0.f,0.f,0.f,0.f}};
    #pragma unroll
    for (int ks = 0; ks < 2; ++ks) {
        uint4 af = *(const uint4*)(Wab + (((ot << 4) + c) << 6) + (ks << 5) + (g << 3));
        #pragma unroll
        for (int i = 0; i < 2; ++i) {
            uint4 pfq = *(const uint4*)((char*)Pb + (((qtb + i) << 4) + c) * 144 + (ks << 6) + (g << 4));
            acc2[i] = MFMA(BC8(af), BC8(pfq), acc2[i]);
        }
    }
    float* ob = out + (size_t)b * CO * NPIX + n0;
    #pragma unroll
    for (int r = 0; r < 4; ++r) {
        int o = (ot << 4) + (g << 2) + r;
        float bias = ba[o];
        #pragma unroll
        for (int i = 0; i < 2; ++i)
            ob[(size_t)o * NPIX + ((qtb + i) << 4) + c] = gm * (acc2[i][r] + bias);
    }
}

extern "C" void kernel_launch(void* const* d_in, const int* in_sizes, int n_in,
                              void* d_out, int out_size, void* d_ws, size_t ws_size,
                              hipStream_t stream) {
    const float* x     = (const float*)d_in[0];
    const float* Wf    = (const float*)d_in[1];
    const float* bf_   = (const float*)d_in[2];
    const float* Wg    = (const float*)d_in[3];
    const float* bg_   = (const float*)d_in[4];
    const float* Wh    = (const float*)d_in[5];
    const float* bh_   = (const float*)d_in[6];
    const float* Wa    = (const float*)d_in[7];
    const float* ba    = (const float*)d_in[8];
    const float* gamma = (const float*)d_in[9];
    float* out = (float*)d_out;

    ushort_t* Wb = (ushort_t*)d_ws;                               // 57344 B
    const size_t matb = (size_t)BATCH * NPIX * CO;                // 1M elems
    ushort_t* Q = (ushort_t*)((char*)d_ws + 65536);               // 2 MB
    ushort_t* K = Q + matb;                                       // 2 MB
    ushort_t* V = K + matb;                                       // 2 MB (transposed [B][64][N])

    wconv_kernel<<<16, 256, 0, stream>>>(Wf, Wg, Wh, Wa, Wb);
    proj_kernel<<<BATCH * (NPIX / 64), 256, 0, stream>>>(x, Wb, bf_, bg_, bh_, Q, K, V);
    flash_kernel<<<BATCH * (NPIX / 64), 512, 0, stream>>>(Q, K, V, Wb, ba, gamma, out);
}

// Round 5
// 75.660 us; speedup vs baseline: 6.9017x; 1.1002x over previous
//
#include <hip/hip_runtime.h>
#include <math.h>

#define BATCH 4
#define CIN   128
#define CO    64
#define NPIX  4096

typedef unsigned int   uint_t;
typedef unsigned short ushort_t;
typedef __bf16 bfx8 __attribute__((ext_vector_type(8)));
typedef float  f32x4 __attribute__((ext_vector_type(4)));

#define MFMA(a,b,c) __builtin_amdgcn_mfma_f32_16x16x32_bf16((a),(b),(c),0,0,0)
#define BC8(x) __builtin_bit_cast(bfx8,(x))

static __device__ __forceinline__ ushort_t f2bf(float f) {
    uint_t u = __builtin_bit_cast(uint_t, f);
    u = (u + 0x7fffu + ((u >> 16) & 1u)) >> 16;   // RNE
    return (ushort_t)u;
}
static __device__ __forceinline__ float bf2f(ushort_t h) {
    return __builtin_bit_cast(float, (uint_t)h << 16);
}
static __device__ __forceinline__ uint_t pk2(float a, float b) {
    return (uint_t)f2bf(a) | ((uint_t)f2bf(b) << 16);
}
static __device__ __forceinline__ uint_t cvtpk(float lo, float hi) {
    uint_t r;
    asm("v_cvt_pk_bf16_f32 %0, %1, %2" : "=v"(r) : "v"(lo), "v"(hi));
    return r;
}
static __device__ __forceinline__ void gload16(const void* g, void* l) {
    __builtin_amdgcn_global_load_lds(
        (const __attribute__((address_space(1))) void*)g,
        (__attribute__((address_space(3))) void*)l, 16, 0, 0);
}

// ---------------- Kernel 0: convert Wf,Wg,Wh,Wa to bf16 in ws ----------------
__global__ __launch_bounds__(256) void wconv_kernel(
    const float* __restrict__ Wf, const float* __restrict__ Wg,
    const float* __restrict__ Wh, const float* __restrict__ Wa,
    ushort_t* __restrict__ Wb)
{
    int gid = blockIdx.x * 256 + threadIdx.x;
    for (int e = gid; e < 28672; e += 4096) {
        float v;
        if      (e < 8192)  v = Wf[e];
        else if (e < 16384) v = Wg[e - 8192];
        else if (e < 24576) v = Wh[e - 16384];
        else                v = Wa[e - 24576];
        Wb[e] = f2bf(v);
    }
}

// ---------------- Kernel 1: MFMA projections (verified R4, unchanged) ----------------
__global__ __launch_bounds__(256) void proj_kernel(
    const float* __restrict__ x, const ushort_t* __restrict__ Wb,
    const float* __restrict__ bf_, const float* __restrict__ bg_, const float* __restrict__ bh_,
    ushort_t* __restrict__ Q, ushort_t* __restrict__ K, ushort_t* __restrict__ V)
{
    __shared__ ushort_t xs[CIN][70];   // hi
    __shared__ ushort_t xl[CIN][70];   // lo

    int bid = blockIdx.x, b = bid >> 6, n0 = (bid & 63) << 6, t = threadIdx.x;
    int w = t >> 6, lane = t & 63, cl = lane & 15, g = (lane >> 4) & 3;

    const float* xb = x + (size_t)b * CIN * NPIX + n0;
    #pragma unroll
    for (int i = 0; i < 8; ++i) {
        int idx = t + (i << 8);
        int cc = idx >> 4, n4 = idx & 15;
        float4 v = *(const float4*)(xb + (size_t)cc * NPIX + (n4 << 2));
        ushort_t h0 = f2bf(v.x), h1 = f2bf(v.y), h2 = f2bf(v.z), h3 = f2bf(v.w);
        ushort_t* dh = &xs[cc][n4 << 2];
        *(uint_t*)dh       = (uint_t)h0 | ((uint_t)h1 << 16);
        *(uint_t*)(dh + 2) = (uint_t)h2 | ((uint_t)h3 << 16);
        ushort_t* dl = &xl[cc][n4 << 2];
        *(uint_t*)dl       = pk2(v.x - bf2f(h0), v.y - bf2f(h1));
        *(uint_t*)(dl + 2) = pk2(v.z - bf2f(h2), v.w - bf2f(h3));
    }
    __syncthreads();

    uint4 aq[4], al[4];
    int col = (w << 4) + cl;
    #pragma unroll
    for (int ks = 0; ks < 4; ++ks) {
        ushort_t av[8], lv[8];
        #pragma unroll
        for (int j = 0; j < 8; ++j) {
            av[j] = xs[(ks << 5) + (g << 3) + j][col];
            lv[j] = xl[(ks << 5) + (g << 3) + j][col];
        }
        uint4 a, l;
        a.x = (uint_t)av[0] | ((uint_t)av[1] << 16);
        a.y = (uint_t)av[2] | ((uint_t)av[3] << 16);
        a.z = (uint_t)av[4] | ((uint_t)av[5] << 16);
        a.w = (uint_t)av[6] | ((uint_t)av[7] << 16);
        l.x = (uint_t)lv[0] | ((uint_t)lv[1] << 16);
        l.y = (uint_t)lv[2] | ((uint_t)lv[3] << 16);
        l.z = (uint_t)lv[4] | ((uint_t)lv[5] << 16);
        l.w = (uint_t)lv[6] | ((uint_t)lv[7] << 16);
        aq[ks] = a; al[ks] = l;
    }

    const float* bps[3] = {bf_, bg_, bh_};
    int nb = n0 + (w << 4);

    for (int p = 0; p < 3; ++p) {
        const ushort_t* Wp = Wb + p * 8192;
        f32x4 acc[4];
        #pragma unroll
        for (int ot = 0; ot < 4; ++ot) acc[ot] = (f32x4){0.f,0.f,0.f,0.f};
        #pragma unroll
        for (int ks = 0; ks < 4; ++ks) {
            #pragma unroll
            for (int ot = 0; ot < 4; ++ot) {
                uint4 bq = *(const uint4*)(Wp + (((ot << 4) + cl) << 7) + (ks << 5) + (g << 3));
                acc[ot] = MFMA(BC8(aq[ks]), BC8(bq), acc[ot]);
                acc[ot] = MFMA(BC8(al[ks]), BC8(bq), acc[ot]);
            }
        }
        if (p < 2) {
            ushort_t* dst = (p == 0 ? Q : K) + ((size_t)b * NPIX + nb) * CO;
            #pragma unroll
            for (int ot = 0; ot < 4; ++ot) {
                float bias = bps[p][(ot << 4) + cl];
                #pragma unroll
                for (int r = 0; r < 4; ++r)
                    dst[(size_t)((g << 2) + r) * CO + (ot << 4) + cl] = f2bf(acc[ot][r] + bias);
            }
        } else {
            #pragma unroll
            for (int ot = 0; ot < 4; ++ot) {
                float bias = bps[p][(ot << 4) + cl];
                uint2 pk;
                pk.x = pk2(acc[ot][0] + bias, acc[ot][1] + bias);
                pk.y = pk2(acc[ot][2] + bias, acc[ot][3] + bias);
                ushort_t* Vd = V + (size_t)b * CO * NPIX + (size_t)((ot << 4) + cl) * NPIX + nb + (g << 2);
                *(uint2*)Vd = pk;
            }
        }
    }
}

// ---------------- Kernel 2: flash attention, 2-phase prefetch + fused outconv ----------------
// 512 thr = 8 waves. h = w>>2 (q-half), ws = w&3 (32-key slice of 128-key tile).
// Dynamic LDS 86016B:
//   buf0 @0:     K [128][64] swz ^key&7 (16K) | Vt [64][128] swz ^d&7 (16K)
//   buf1 @32768: same (16K+16K)
//   P    @65536: per-wave [32q][32k] bf16 pitch 80B (8 x 2560B)
// Staging = global_load_lds, linear LDS dest + pre-swizzled global source.
// Epilogue overlays: mlb/llb @65536 (on dead P); Po f32 @0; Pb bf16 @16384.
#define PREG 65536

__global__ __launch_bounds__(512, 1) void flash_kernel(
    const ushort_t* __restrict__ Q, const ushort_t* __restrict__ K,
    const ushort_t* __restrict__ V, const ushort_t* __restrict__ Wb,
    const float* __restrict__ ba, const float* __restrict__ gamma,
    float* __restrict__ out)
{
    extern __shared__ __align__(16) char smem[];

    int orig = blockIdx.x;
    int bid = ((orig & 7) << 5) | (orig >> 3);      // XCD swizzle: 2 XCDs per batch
    int b = bid >> 6, n0 = (bid & 63) << 6, t = threadIdx.x;
    int w = t >> 6, lane = t & 63, c = lane & 15, g = (lane >> 4) & 3;
    int h = w >> 2, ws = w & 3;

    const ushort_t* Qb = Q + ((size_t)b * NPIX + n0) * CO;
    const ushort_t* Kb = K + (size_t)b * NPIX * CO;
    const ushort_t* Vb = V + (size_t)b * CO * NPIX;

    uint4 qf[2][2];
    #pragma unroll
    for (int qs = 0; qs < 2; ++qs)
        #pragma unroll
        for (int ds = 0; ds < 2; ++ds)
            qf[qs][ds] = *(const uint4*)(Qb + ((h << 5) + (qs << 4) + c) * CO + (ds << 5) + (g << 3));

    f32x4 oac[4][2];
    #pragma unroll
    for (int i = 0; i < 4; ++i)
        #pragma unroll
        for (int j = 0; j < 2; ++j) oac[i][j] = (f32x4){0.f,0.f,0.f,0.f};
    float mreg[2] = {-INFINITY, -INFINITY};
    float lreg[2] = {0.f, 0.f};

    char* Pmy = smem + PREG + w * 2560;

    // stage tile kt into buf: linear LDS dest, inverse-swizzled global source
    auto STAGE = [&](char* buf, int kt) {
        #pragma unroll
        for (int i = 0; i < 2; ++i) {
            int cb = (((w << 1) + i) << 6);          // wave-uniform chunk base
            int ci = cb | lane;
            int key = ci >> 3, kc = (ci & 7) ^ (key & 7);
            gload16(Kb + (size_t)((kt << 7) + key) * CO + (kc << 3), buf + (cb << 4));
            int d = ci >> 4, vc = (ci & 15) ^ (d & 7);
            gload16(Vb + (size_t)d * NPIX + (kt << 7) + (vc << 3), buf + 16384 + (cb << 4));
        }
    };

    STAGE(smem, 0);
    __syncthreads();                                 // compiler drains vmcnt before barrier

    int cur = 0;
    for (int kt = 0; kt < 32; ++kt) {
        char* bufc = smem + (cur << 15);
        if (kt + 1 < 32) STAGE(smem + ((cur ^ 1) << 15), kt + 1);

        // ---- QK^T: S[key][q] for 32-key slice ws ----
        f32x4 sac[2][2];
        #pragma unroll
        for (int s = 0; s < 2; ++s)
            #pragma unroll
            for (int qs = 0; qs < 2; ++qs) sac[s][qs] = (f32x4){0.f,0.f,0.f,0.f};
        __builtin_amdgcn_s_setprio(1);
        #pragma unroll
        for (int s = 0; s < 2; ++s) {
            int key = (ws << 5) + (s << 4) + c;
            int sw = key & 7;
            uint4 kf0 = *(const uint4*)(bufc + (key << 7) + ((g ^ sw) << 4));
            uint4 kf1 = *(const uint4*)(bufc + (key << 7) + (((4 | g) ^ sw) << 4));
            #pragma unroll
            for (int qs = 0; qs < 2; ++qs) {
                sac[s][qs] = MFMA(BC8(kf0), BC8(qf[qs][0]), sac[s][qs]);
                sac[s][qs] = MFMA(BC8(kf1), BC8(qf[qs][1]), sac[s][qs]);
            }
        }
        __builtin_amdgcn_s_setprio(0);

        // ---- online softmax with defer-max (THR=8) ----
        float mx[2], ps[2][8];
        #pragma unroll
        for (int qs = 0; qs < 2; ++qs) {
            float v = sac[0][qs][0];
            #pragma unroll
            for (int j = 1; j < 4; ++j) v = fmaxf(v, sac[0][qs][j]);
            #pragma unroll
            for (int j = 0; j < 4; ++j) v = fmaxf(v, sac[1][qs][j]);
            v = fmaxf(v, __shfl_xor(v, 16));
            v = fmaxf(v, __shfl_xor(v, 32));
            mx[qs] = v;
        }
        bool defer = (mx[0] <= mreg[0] + 8.f) && (mx[1] <= mreg[1] + 8.f);
        if (!__all(defer)) {
            #pragma unroll
            for (int qs = 0; qs < 2; ++qs) {
                float mn = fmaxf(mreg[qs], mx[qs]);
                float r  = __expf(mreg[qs] - mn);
                lreg[qs] *= r;
                #pragma unroll
                for (int ds = 0; ds < 4; ++ds) oac[ds][qs] *= r;
                mreg[qs] = mn;
            }
        }
        #pragma unroll
        for (int qs = 0; qs < 2; ++qs) {
            float ls = 0.f;
            #pragma unroll
            for (int s = 0; s < 2; ++s)
                #pragma unroll
                for (int j = 0; j < 4; ++j) {
                    float p = __expf(sac[s][qs][j] - mreg[qs]);
                    ps[qs][(s << 2) + j] = p; ls += p;
                }
            ls += __shfl_xor(ls, 16);
            ls += __shfl_xor(ls, 32);
            lreg[qs] += ls;
            int ql = (qs << 4) + c;
            #pragma unroll
            for (int s = 0; s < 2; ++s) {
                uint2 pk;
                pk.x = cvtpk(ps[qs][(s << 2) + 0], ps[qs][(s << 2) + 1]);
                pk.y = cvtpk(ps[qs][(s << 2) + 2], ps[qs][(s << 2) + 3]);
                *(uint2*)(Pmy + ql * 80 + (s << 5) + (g << 3)) = pk;
            }
        }

        // ---- PV over the wave's 32-key slice ----
        uint4 vf[4], pf[2];
        #pragma unroll
        for (int ds = 0; ds < 4; ++ds) {
            int d = (ds << 4) + c;
            vf[ds] = *(const uint4*)(bufc + 16384 + (d << 8) + ((((ws << 2) | g) ^ (d & 7)) << 4));
        }
        #pragma unroll
        for (int qs = 0; qs < 2; ++qs)
            pf[qs] = *(const uint4*)(Pmy + ((qs << 4) + c) * 80 + (g << 4));
        __builtin_amdgcn_s_setprio(1);
        #pragma unroll
        for (int ds = 0; ds < 4; ++ds)
            #pragma unroll
            for (int qs = 0; qs < 2; ++qs)
                oac[ds][qs] = MFMA(BC8(vf[ds]), BC8(pf[qs]), oac[ds][qs]);
        __builtin_amdgcn_s_setprio(0);

        __syncthreads();                 // all waves done with bufc; next tile's loads landed
        cur ^= 1;
    }

    // ---- stats exchange ----
    float* mlb = (float*)(smem + PREG);
    float* llb = (float*)(smem + PREG + 2048);
    if (lane < 16) {
        #pragma unroll
        for (int qs = 0; qs < 2; ++qs) {
            mlb[(w << 6) + (h << 5) + (qs << 4) + lane] = mreg[qs];
            llb[(w << 6) + (h << 5) + (qs << 4) + lane] = lreg[qs];
        }
    }
    __syncthreads();

    float fac[2];
    #pragma unroll
    for (int qs = 0; qs < 2; ++qs) {
        int q = (h << 5) + (qs << 4) + c;
        int base = h << 2;
        float m0 = mlb[((base + 0) << 6) + q], m1 = mlb[((base + 1) << 6) + q];
        float m2 = mlb[((base + 2) << 6) + q], m3 = mlb[((base + 3) << 6) + q];
        float M  = fmaxf(fmaxf(m0, m1), fmaxf(m2, m3));
        float a0 = __expf(m0 - M), a1 = __expf(m1 - M), a2 = __expf(m2 - M), a3 = __expf(m3 - M);
        float L  = a0 * llb[((base + 0) << 6) + q] + a1 * llb[((base + 1) << 6) + q]
                 + a2 * llb[((base + 2) << 6) + q] + a3 * llb[((base + 3) << 6) + q];
        float aw = (ws == 0) ? a0 : (ws == 1) ? a1 : (ws == 2) ? a2 : a3;
        fac[qs] = aw / L;
    }
    #pragma unroll
    for (int ds = 0; ds < 4; ++ds)
        #pragma unroll
        for (int qs = 0; qs < 2; ++qs) oac[ds][qs] *= fac[qs];

    // ---- accumulate scaled partials into Po f32 @0, rounds ws = 0,1,2 ----
    for (int r = 0; r < 3; ++r) {
        if (ws == r) {
            #pragma unroll
            for (int ds = 0; ds < 4; ++ds)
                #pragma unroll
                for (int qs = 0; qs < 2; ++qs) {
                    int q = (h << 5) + (qs << 4) + c;
                    int off = (q << 8) + ((((ds << 2) | g) ^ (q & 7)) << 4);
                    f32x4 v = oac[ds][qs];
                    if (r > 0) v += *(const f32x4*)(smem + off);
                    *(f32x4*)(smem + off) = v;
                }
        }
        __syncthreads();
    }
    // round 3: final add -> bf16 Pb @16384
    ushort_t* Pb = (ushort_t*)(smem + 16384);
    if (ws == 3) {
        #pragma unroll
        for (int ds = 0; ds < 4; ++ds)
            #pragma unroll
            for (int qs = 0; qs < 2; ++qs) {
                int q = (h << 5) + (qs << 4) + c;
                int off = (q << 8) + ((((ds << 2) | g) ^ (q & 7)) << 4);
                f32x4 v = oac[ds][qs] + *(const f32x4*)(smem + off);
                uint2 pk;
                pk.x = pk2(v[0], v[1]);
                pk.y = pk2(v[2], v[3]);
                *(uint2*)(Pb + q * 72 + (ds << 4) + (g << 2)) = pk;
            }
    }
    __syncthreads();

    // ---- fused outconv: out[o][q] = gamma*(Wa[o][:] . Pb[q][:] + ba[o]) ----
    const ushort_t* Wab = Wb + 24576;
    float gm = gamma[0];
    int ot = w >> 1, qtb = (w & 1) << 1;
    f32x4 acc2[2] = {(f32x4){0.f,0.f,0.f,0.f}, (f32x4){0.f,0.f,0.f,0.f}};
    #pragma unroll
    for (int ks = 0; ks < 2; ++ks) {
        uint4 af = *(const uint4*)(Wab + (((ot << 4) + c) << 6) + (ks << 5) + (g << 3));
        #pragma unroll
        for (int i = 0; i < 2; ++i) {
            uint4 pfq = *(const uint4*)((char*)Pb + (((qtb + i) << 4) + c) * 144 + (ks << 6) + (g << 4));
            acc2[i] = MFMA(BC8(af), BC8(pfq), acc2[i]);
        }
    }
    float* ob = out + (size_t)b * CO * NPIX + n0;
    #pragma unroll
    for (int r = 0; r < 4; ++r) {
        int o = (ot << 4) + (g << 2) + r;
        float bias = ba[o];
        #pragma unroll
        for (int i = 0; i < 2; ++i)
            ob[(size_t)o * NPIX + ((qtb + i) << 4) + c] = gm * (acc2[i][r] + bias);
    }
}

extern "C" void kernel_launch(void* const* d_in, const int* in_sizes, int n_in,
                              void* d_out, int out_size, void* d_ws, size_t ws_size,
                              hipStream_t stream) {
    const float* x     = (const float*)d_in[0];
    const float* Wf    = (const float*)d_in[1];
    const float* bf_   = (const float*)d_in[2];
    const float* Wg    = (const float*)d_in[3];
    const float* bg_   = (const float*)d_in[4];
    const float* Wh    = (const float*)d_in[5];
    const float* bh_   = (const float*)d_in[6];
    const float* Wa    = (const float*)d_in[7];
    const float* ba    = (const float*)d_in[8];
    const float* gamma = (const float*)d_in[9];
    float* out = (float*)d_out;

    ushort_t* Wb = (ushort_t*)d_ws;                               // 57344 B
    const size_t matb = (size_t)BATCH * NPIX * CO;                // 1M elems
    ushort_t* Q = (ushort_t*)((char*)d_ws + 65536);               // 2 MB
    ushort_t* K = Q + matb;                                       // 2 MB
    ushort_t* V = K + matb;                                       // 2 MB (transposed [B][64][N])

    wconv_kernel<<<16, 256, 0, stream>>>(Wf, Wg, Wh, Wa, Wb);
    proj_kernel<<<BATCH * (NPIX / 64), 256, 0, stream>>>(x, Wb, bf_, bg_, bh_, Q, K, V);
    flash_kernel<<<BATCH * (NPIX / 64), 512, 86016, stream>>>(Q, K, V, Wb, ba, gamma, out);
}